// Round 5
// baseline (537.459 us; speedup 1.0000x reference)
//
#include <hip/hip_runtime.h>
#include <hip/hip_bf16.h>

typedef __attribute__((ext_vector_type(8))) short bf16x8;
typedef __attribute__((ext_vector_type(4))) float f32x4;

__device__ __forceinline__ unsigned short f2b(float f) {
    unsigned int u = __float_as_uint(f);
    unsigned int r = u + 0x7FFFu + ((u >> 16) & 1u);
    return (unsigned short)(r >> 16);
}

__device__ __forceinline__ float gelu_erf(float v) {
    return 0.5f * v * (1.0f + erff(v * 0.70710678118654752f));
}

// async global->LDS, 16B per lane. LDS dest must be wave-uniform; HW adds lane*16.
__device__ __forceinline__ void gload_lds16(const void* g, void* l) {
    __builtin_amdgcn_global_load_lds(
        (const __attribute__((address_space(1))) void*)g,
        (__attribute__((address_space(3))) void*)l, 16, 0, 0);
}

// ---------------- cast fp32 -> bf16 (vectorized x4, optional scale) ----------------
__global__ void cast_bf16_k(const float* __restrict__ src, unsigned short* __restrict__ dst,
                            int n4, float scale) {
    int i = blockIdx.x * blockDim.x + threadIdx.x;
    if (i < n4) {
        float4 v = ((const float4*)src)[i];
        ushort4 o;
        o.x = f2b(v.x * scale); o.y = f2b(v.y * scale);
        o.z = f2b(v.z * scale); o.w = f2b(v.w * scale);
        ((ushort4*)dst)[i] = o;
    }
}

// ---------------- RMSNorm fp32 -> bf16, D=1024, one block per row ----------------
__global__ void rmsnorm_bf16_k(const float* __restrict__ x, const float* __restrict__ g,
                               unsigned short* __restrict__ out) {
    int row = blockIdx.x;
    int t = threadIdx.x;  // 256
    const float4* xr = (const float4*)(x + (size_t)row * 1024);
    float4 xv = xr[t];
    float ss = xv.x * xv.x + xv.y * xv.y + xv.z * xv.z + xv.w * xv.w;
    #pragma unroll
    for (int off = 32; off; off >>= 1) ss += __shfl_xor(ss, off, 64);
    __shared__ float red[4];
    int wave = t >> 6, lane = t & 63;
    if (lane == 0) red[wave] = ss;
    __syncthreads();
    float tot = red[0] + red[1] + red[2] + red[3];
    float rn = rsqrtf(tot * (1.0f / 1024.0f) + 1e-5f);
    float4 gv = ((const float4*)g)[t];
    ushort4 o4;
    o4.x = f2b(xv.x * rn * gv.x);
    o4.y = f2b(xv.y * rn * gv.y);
    o4.z = f2b(xv.z * rn * gv.z);
    o4.w = f2b(xv.w * rn * gv.w);
    ((ushort4*)out)[(size_t)row * 256 + t] = o4;
}

// ---------------- V transpose: qkv V-part [s][d] -> vt[(bh*64+d)][s] ----------------
__global__ void vtrans_k(const unsigned short* __restrict__ qkv, unsigned short* __restrict__ vt) {
    __shared__ unsigned short Ls[64 * 72];
    int st = blockIdx.x, bh = blockIdx.y, b = bh >> 4, h = bh & 15;
    int s0 = st * 64;
    int tid = threadIdx.x;
    const unsigned short* Vg = qkv + (size_t)(b * 2048 + s0) * 3072 + 2048 + h * 64;
    #pragma unroll
    for (int i = 0; i < 2; i++) {
        int idx = i * 256 + tid;
        int r = idx >> 3, c8 = (idx & 7) * 8;
        *(uint4*)&Ls[r * 72 + c8] = *(const uint4*)&Vg[(size_t)r * 3072 + c8];
    }
    __syncthreads();
    #pragma unroll
    for (int i = 0; i < 2; i++) {
        int idx = i * 256 + tid;
        int d = idx >> 3, s8 = (idx & 7) * 8;
        unsigned short tmp[8];
        #pragma unroll
        for (int j = 0; j < 8; j++) tmp[j] = Ls[(s8 + j) * 72 + d];
        *(uint4*)&vt[(size_t)(bh * 64 + d) * 2048 + s0 + s8] = *(uint4*)tmp;
    }
}

// ---------------- GEMM  C[M,N] = A[M,K] * B[N,K]^T, 128x128 tile ----------------
// XOR-swizzled LDS; global_load_lds width-16 staging; LDS-transposed epilogue.
// EPI: 0 = store bf16, 1 = store fp32 (res + acc), 2 = gelu -> bf16
template <int EPI>
__launch_bounds__(256)
__global__ void gemm_bt(const unsigned short* __restrict__ A, const unsigned short* __restrict__ B,
                        const float* __restrict__ res, void* __restrict__ out,
                        int M, int N, int K) {
    __shared__ __align__(16) unsigned short smem[2 * 128 * 32];  // 16 KB
    unsigned short* As = smem;
    unsigned short* Bs = smem + 128 * 32;

    int tid = threadIdx.x;
    int wave = tid >> 6, lane = tid & 63;
    int lrow = lane & 15, quad = lane >> 4;
    int qx8 = (quad ^ ((lrow >> 1) & 3)) * 8;

    int gx = gridDim.x, gy = gridDim.y;
    int cid = blockIdx.y * gx + blockIdx.x;
    int per = (gx * gy) >> 3;
    int nid = (cid & 7) * per + (cid >> 3);
    const int CG = 8;
    int group = nid / (CG * gy);
    int rem = nid % (CG * gy);
    int bxs = group * CG + (rem % CG);
    int bys = rem / CG;
    int bm = bys * 128, bn = bxs * 128;

    int wm = (wave & 1) * 64, wn = (wave >> 1) * 64;

    const unsigned short* Ab = A + (size_t)bm * K;
    const unsigned short* Bb = B + (size_t)bn * K;

    f32x4 zero = {0.f, 0.f, 0.f, 0.f};
    f32x4 acc[4][4];
    #pragma unroll
    for (int mi = 0; mi < 4; mi++)
        #pragma unroll
        for (int ni = 0; ni < 4; ni++) acc[mi][ni] = zero;

    int wbase = tid & 192;

    for (int k0 = 0; k0 < K; k0 += 32) {
        if (k0) __syncthreads();
        #pragma unroll
        for (int i = 0; i < 2; i++) {
            int idx = i * 256 + tid;
            int r = idx >> 2;
            int c = ((idx & 3) ^ ((idx >> 3) & 3)) * 8;  // swizzled chunk
            gload_lds16(&Ab[(size_t)r * K + k0 + c], As + ((size_t)(i * 256 + wbase)) * 8);
            gload_lds16(&Bb[(size_t)r * K + k0 + c], Bs + ((size_t)(i * 256 + wbase)) * 8);
        }
        __syncthreads();

        bf16x8 af[4], bfr[4];
        #pragma unroll
        for (int mi = 0; mi < 4; mi++)
            af[mi] = *(const bf16x8*)&As[(wm + mi * 16 + lrow) * 32 + qx8];
        #pragma unroll
        for (int ni = 0; ni < 4; ni++)
            bfr[ni] = *(const bf16x8*)&Bs[(wn + ni * 16 + lrow) * 32 + qx8];
        #pragma unroll
        for (int mi = 0; mi < 4; mi++)
            #pragma unroll
            for (int ni = 0; ni < 4; ni++)
                acc[mi][ni] = __builtin_amdgcn_mfma_f32_16x16x32_bf16(af[mi], bfr[ni], acc[mi][ni], 0, 0, 0);
    }

    float* Cs = (float*)smem;
    int row16 = lane >> 2, cseg = (lane & 3) * 16;
    #pragma unroll
    for (int p = 0; p < 4; p++) {
        __syncthreads();
        #pragma unroll
        for (int ni = 0; ni < 4; ni++)
            #pragma unroll
            for (int r = 0; r < 4; r++)
                Cs[wave * 1024 + (quad * 4 + r) * 64 + ni * 16 + lrow] = acc[p][ni][r];
        __syncthreads();
        const float* src = &Cs[wave * 1024 + row16 * 64 + cseg];
        int grow = bm + wm + p * 16 + row16;
        int gcol = bn + wn + cseg;
        size_t off = (size_t)grow * N + gcol;
        if (EPI == 1) {
            float* op = (float*)out + off;
            const float* rp = res + off;
            #pragma unroll
            for (int j = 0; j < 4; j++) {
                float4 v = ((const float4*)src)[j];
                float4 rr = ((const float4*)rp)[j];
                v.x += rr.x; v.y += rr.y; v.z += rr.z; v.w += rr.w;
                ((float4*)op)[j] = v;
            }
        } else {
            unsigned short tmp[16];
            #pragma unroll
            for (int j = 0; j < 16; j++) {
                float v = src[j];
                if (EPI == 2) v = gelu_erf(v);
                tmp[j] = f2b(v);
            }
            unsigned short* op = (unsigned short*)out + off;
            *(uint4*)op = *(uint4*)tmp;
            *(uint4*)(op + 8) = *(uint4*)(tmp + 8);
        }
    }
}

// ---------------- GEMM 128x64 tile (N=1024: 512 blocks) ----------------
__launch_bounds__(256)
__global__ void gemm_bt64(const unsigned short* __restrict__ A, const unsigned short* __restrict__ B,
                          const float* __restrict__ res, float* __restrict__ out,
                          int M, int N, int K) {
    __shared__ __align__(16) unsigned short As[128 * 32];  // 8KB
    __shared__ __align__(16) unsigned short Bs[64 * 32];   // 4KB

    int tid = threadIdx.x, wave = tid >> 6, lane = tid & 63;
    int lrow = lane & 15, quad = lane >> 4;
    int qx8 = (quad ^ ((lrow >> 1) & 3)) * 8;

    int gx = gridDim.x, gy = gridDim.y;
    int cid = blockIdx.y * gx + blockIdx.x;
    int per = (gx * gy) >> 3;
    int nid = (cid & 7) * per + (cid >> 3);
    const int CG = 8;
    int group = nid / (CG * gy);
    int rem = nid % (CG * gy);
    int bxs = group * CG + (rem % CG);
    int bys = rem / CG;
    int bm = bys * 128, bn = bxs * 64;

    int wm = (wave & 1) * 64, wn = (wave >> 1) * 32;

    f32x4 zero = {0.f, 0.f, 0.f, 0.f};
    f32x4 acc[4][2];
    #pragma unroll
    for (int mi = 0; mi < 4; mi++)
        #pragma unroll
        for (int ni = 0; ni < 2; ni++) acc[mi][ni] = zero;

    int rr4 = lane >> 2;
    int c8s = ((lane & 3) ^ ((lane >> 3) & 3)) * 8;
    const unsigned short* Ab = A + (size_t)(bm + wave * 32 + rr4) * K + c8s;
    const unsigned short* Bb = B + (size_t)(bn + wave * 16 + rr4) * K + c8s;

    for (int k0 = 0; k0 < K; k0 += 32) {
        if (k0) __syncthreads();
        gload_lds16(Ab + k0, &As[(wave * 32) * 32]);
        gload_lds16(Ab + (size_t)16 * K + k0, &As[(wave * 32 + 16) * 32]);
        gload_lds16(Bb + k0, &Bs[(wave * 16) * 32]);
        __syncthreads();

        bf16x8 af[4], bfr[2];
        #pragma unroll
        for (int mi = 0; mi < 4; mi++)
            af[mi] = *(const bf16x8*)&As[(wm + mi * 16 + lrow) * 32 + qx8];
        #pragma unroll
        for (int ni = 0; ni < 2; ni++)
            bfr[ni] = *(const bf16x8*)&Bs[(wn + ni * 16 + lrow) * 32 + qx8];
        #pragma unroll
        for (int mi = 0; mi < 4; mi++)
            #pragma unroll
            for (int ni = 0; ni < 2; ni++)
                acc[mi][ni] = __builtin_amdgcn_mfma_f32_16x16x32_bf16(af[mi], bfr[ni], acc[mi][ni], 0, 0, 0);
    }

    float* Cs = (float*)As;
    int row16 = lane >> 2, cseg = (lane & 3) * 8;
    #pragma unroll
    for (int p = 0; p < 4; p++) {
        __syncthreads();
        #pragma unroll
        for (int ni = 0; ni < 2; ni++)
            #pragma unroll
            for (int r = 0; r < 4; r++)
                Cs[wave * 512 + (quad * 4 + r) * 32 + ni * 16 + lrow] = acc[p][ni][r];
        __syncthreads();
        const float* src = &Cs[wave * 512 + row16 * 32 + cseg];
        int grow = bm + wm + p * 16 + row16;
        int gcol = bn + wn + cseg;
        size_t off = (size_t)grow * N + gcol;
        float* op = out + off;
        const float* rp = res + off;
        #pragma unroll
        for (int j = 0; j < 2; j++) {
            float4 v = ((const float4*)src)[j];
            float4 rv = ((const float4*)rp)[j];
            v.x += rv.x; v.y += rv.y; v.z += rv.z; v.w += rv.w;
            ((float4*)op)[j] = v;
        }
    }
}

// ---------------- Flash attention, causal, DK=64, BARRIER-FREE ----------------
// Each wave is fully independent: 16 queries/wave, K and V^T fragments loaded
// directly global->registers (L2-resident), P transposed through wave-private LDS.
// S^T form: s = mfma(K_frag, Q_frag) puts 4 consecutive keys per lane ->
// P-write is 4x ds_write_b64. Fixed-max softmax (wq pre-scaled by 0.125*log2e),
// scalar per-lane l, reductions only at kernel end. grid (32,32), qt = 31-bx.
__launch_bounds__(256)
__global__ void attn_k(const unsigned short* __restrict__ qkv,
                       const unsigned short* __restrict__ vt,
                       unsigned short* __restrict__ attn_out) {
    const int ROWQKV = 3072;
    int qt = (int)(gridDim.x - 1 - blockIdx.x);  // 31..0, long first
    int bh = blockIdx.y;
    int b = bh >> 4, h = bh & 15;
    int q0 = qt * 64;

    __shared__ __align__(16) unsigned short Ps[4][16 * 72];  // 9 KB, wave-private

    int tid = threadIdx.x, wave = tid >> 6, lane = tid & 63;
    int lrow = lane & 15, quad = lane >> 4;

    size_t base = (size_t)b * 2048 * ROWQKV;

    // Q B-fragments (query = q0 + wave*16 + lrow, dk = quad*8..): loop-invariant
    const unsigned short* Qg = qkv + base + (size_t)(q0 + wave * 16 + lrow) * ROWQKV + h * 64 + quad * 8;
    bf16x8 qf0 = *(const bf16x8*)Qg;
    bf16x8 qf1 = *(const bf16x8*)(Qg + 32);

    // K A-frag base: key row = lrow (+ kt*64 + ni*16), dk col = quad*8 (+ half*32)
    const unsigned short* Kg = qkv + base + (size_t)lrow * ROWQKV + 1024 + h * 64 + quad * 8;
    // V B-frag base: d row = lrow (+ ni*16), key col = quad*8 (+ kt*64 + ks*32)
    const unsigned short* Vg = vt + (size_t)(bh * 64 + lrow) * 2048 + quad * 8;

    f32x4 zero = {0.f, 0.f, 0.f, 0.f};
    f32x4 o[4];
    #pragma unroll
    for (int ni = 0; ni < 4; ni++) o[ni] = zero;
    float l = 0.f;

    unsigned short* Pw = Ps[wave];
    int qloc = wave * 16 + lrow;  // query index within the 64-query block

    for (int kt = 0; kt <= qt; kt++) {
        const unsigned short* Kt = Kg + (size_t)(kt * 64) * ROWQKV;
        const unsigned short* Vt = Vg + kt * 64;

        // K fragments (8 x 16B, independent loads)
        bf16x8 kf[4][2];
        #pragma unroll
        for (int ni = 0; ni < 4; ni++) {
            kf[ni][0] = *(const bf16x8*)(Kt + (size_t)(ni * 16) * ROWQKV);
            kf[ni][1] = *(const bf16x8*)(Kt + (size_t)(ni * 16) * ROWQKV + 32);
        }
        // V fragments (independent of softmax -> load early)
        bf16x8 vf[4][2];
        #pragma unroll
        for (int ni = 0; ni < 4; ni++) {
            vf[ni][0] = *(const bf16x8*)(Vt + (size_t)(ni * 16) * 2048);
            vf[ni][1] = *(const bf16x8*)(Vt + (size_t)(ni * 16) * 2048 + 32);
        }

        // S^T = K Q^T : lane holds S[query=lrow][key = kt*64 + ni*16 + quad*4 + r]
        f32x4 s[4];
        #pragma unroll
        for (int ni = 0; ni < 4; ni++) s[ni] = zero;
        #pragma unroll
        for (int ni = 0; ni < 4; ni++)
            s[ni] = __builtin_amdgcn_mfma_f32_16x16x32_bf16(kf[ni][0], qf0, s[ni], 0, 0, 0);
        #pragma unroll
        for (int ni = 0; ni < 4; ni++)
            s[ni] = __builtin_amdgcn_mfma_f32_16x16x32_bf16(kf[ni][1], qf1, s[ni], 0, 0, 0);

        // fixed-max softmax numerator (scale folded into wq)
        if (kt == qt) {
            #pragma unroll
            for (int ni = 0; ni < 4; ni++)
                #pragma unroll
                for (int r = 0; r < 4; r++) {
                    float p = exp2f(s[ni][r]);
                    if (ni * 16 + quad * 4 + r > qloc) p = 0.f;
                    s[ni][r] = p;
                    l += p;
                }
        } else {
            #pragma unroll
            for (int ni = 0; ni < 4; ni++)
                #pragma unroll
                for (int r = 0; r < 4; r++) {
                    float p = exp2f(s[ni][r]);
                    s[ni][r] = p;
                    l += p;
                }
        }

        // P -> wave-private LDS: 4 consecutive keys per lane -> ds_write_b64
        #pragma unroll
        for (int ni = 0; ni < 4; ni++) {
            uint2 pk;
            pk.x = (unsigned int)f2b(s[ni][0]) | ((unsigned int)f2b(s[ni][1]) << 16);
            pk.y = (unsigned int)f2b(s[ni][2]) | ((unsigned int)f2b(s[ni][3]) << 16);
            *(uint2*)&Pw[lrow * 72 + ni * 16 + quad * 4] = pk;
        }
        // read back in A-layout (query=lrow rows, 8 consecutive keys)
        bf16x8 p0 = *(const bf16x8*)&Pw[lrow * 72 + quad * 8];
        bf16x8 p1 = *(const bf16x8*)&Pw[lrow * 72 + 32 + quad * 8];

        // O += P V
        #pragma unroll
        for (int ni = 0; ni < 4; ni++)
            o[ni] = __builtin_amdgcn_mfma_f32_16x16x32_bf16(p0, vf[ni][0], o[ni], 0, 0, 0);
        #pragma unroll
        for (int ni = 0; ni < 4; ni++)
            o[ni] = __builtin_amdgcn_mfma_f32_16x16x32_bf16(p1, vf[ni][1], o[ni], 0, 0, 0);
    }

    // l: sum the 4 quads (same lrow) -> full denominator for query lrow
    l += __shfl_xor(l, 16, 64);
    l += __shfl_xor(l, 32, 64);

    // epilogue: o[ni][r] is O[query = quad*4+r][d = ni*16+lrow]
    #pragma unroll
    for (int r = 0; r < 4; r++) {
        float lr = __shfl(l, quad * 4 + r, 64);  // lane (quad*4+r) has l for that query
        float inv = 1.0f / lr;
        int q = q0 + wave * 16 + quad * 4 + r;
        #pragma unroll
        for (int ni = 0; ni < 4; ni++)
            attn_out[((size_t)b * 2048 + q) * 1024 + h * 64 + ni * 16 + lrow] = f2b(o[ni][r] * inv);
    }
}

extern "C" void kernel_launch(void* const* d_in, const int* in_sizes, int n_in,
                              void* d_out, int out_size, void* d_ws, size_t ws_size,
                              hipStream_t stream) {
    const float* x  = (const float*)d_in[0];
    const float* g1 = (const float*)d_in[1];
    const float* g2 = (const float*)d_in[2];
    const float* wq = (const float*)d_in[3];
    const float* wk = (const float*)d_in[4];
    const float* wv = (const float*)d_in[5];
    const float* wo = (const float*)d_in[6];
    const float* w1 = (const float*)d_in[7];
    const float* w2 = (const float*)d_in[8];
    float* out = (float*)d_out;

    const size_t BS = 4096;
    const size_t D = 1024, DFF = 4096;
    const float QSCALE = 0.18033688011112042f;  // 0.125 * log2(e), folded into wq

    char* w = (char*)d_ws;
    unsigned short* xn_b   = (unsigned short*)w; w += BS * D * 2;
    unsigned short* wqkv_b = (unsigned short*)w; w += 3 * D * D * 2;
    unsigned short* qkv_b  = (unsigned short*)w; w += BS * 3 * D * 2;
    unsigned short* vt_b   = (unsigned short*)w; w += BS * D * 2;
    unsigned short* attn_b = (unsigned short*)w; w += BS * D * 2;
    unsigned short* wo_b   = (unsigned short*)w; w += D * D * 2;
    float*          x2     = (float*)w;          w += BS * D * 4;
    unsigned short* xn2_b  = (unsigned short*)w; w += BS * D * 2;
    unsigned short* w1_b   = (unsigned short*)w; w += DFF * D * 2;
    unsigned short* h_b    = (unsigned short*)w; w += BS * DFF * 2;
    unsigned short* w2_b   = (unsigned short*)w; w += D * DFF * 2;

    int nW = (int)(D * D / 4);
    cast_bf16_k<<<(nW + 255) / 256, 256, 0, stream>>>(wq, wqkv_b, nW, QSCALE);
    cast_bf16_k<<<(nW + 255) / 256, 256, 0, stream>>>(wk, wqkv_b + D * D, nW, 1.0f);
    cast_bf16_k<<<(nW + 255) / 256, 256, 0, stream>>>(wv, wqkv_b + 2 * D * D, nW, 1.0f);
    cast_bf16_k<<<(nW + 255) / 256, 256, 0, stream>>>(wo, wo_b, nW, 1.0f);
    int nF = (int)(DFF * D / 4);
    cast_bf16_k<<<(nF + 255) / 256, 256, 0, stream>>>(w1, w1_b, nF, 1.0f);
    cast_bf16_k<<<(nF + 255) / 256, 256, 0, stream>>>(w2, w2_b, nF, 1.0f);

    rmsnorm_bf16_k<<<(int)BS, 256, 0, stream>>>(x, g1, xn_b);

    // qkv = xn @ [wq;wk;wv]^T   [4096 x 3072]
    gemm_bt<0><<<dim3(24, 32), 256, 0, stream>>>(xn_b, wqkv_b, nullptr, qkv_b, 4096, 3072, 1024);

    // V transpose for attention B-frags
    vtrans_k<<<dim3(32, 32), 256, 0, stream>>>(qkv_b, vt_b);

    // causal flash attention (64 queries/block, barrier-free)
    attn_k<<<dim3(32, 32), 256, 0, stream>>>(qkv_b, vt_b, attn_b);

    // x2 = x + attn @ wo^T
    gemm_bt64<<<dim3(16, 32), 256, 0, stream>>>(attn_b, wo_b, x, x2, 4096, 1024, 1024);

    rmsnorm_bf16_k<<<(int)BS, 256, 0, stream>>>(x2, g2, xn2_b);

    // h = gelu(xn2 @ w1^T)   [4096 x 4096]
    gemm_bt<2><<<dim3(32, 32), 256, 0, stream>>>(xn2_b, w1_b, nullptr, h_b, 4096, 4096, 1024);

    // out = x2 + h @ w2^T
    gemm_bt64<<<dim3(16, 32), 256, 0, stream>>>(h_b, w2_b, x2, out, 4096, 1024, 4096);
}

// Round 6
// 378.868 us; speedup vs baseline: 1.4186x; 1.4186x over previous
//
#include <hip/hip_runtime.h>
#include <hip/hip_bf16.h>

typedef __attribute__((ext_vector_type(8))) short bf16x8;
typedef __attribute__((ext_vector_type(4))) float f32x4;

__device__ __forceinline__ unsigned short f2b(float f) {
    unsigned int u = __float_as_uint(f);
    unsigned int r = u + 0x7FFFu + ((u >> 16) & 1u);
    return (unsigned short)(r >> 16);
}

__device__ __forceinline__ float gelu_erf(float v) {
    return 0.5f * v * (1.0f + erff(v * 0.70710678118654752f));
}

// async global->LDS, 16B per lane. LDS dest must be wave-uniform; HW adds lane*16.
__device__ __forceinline__ void gload_lds16(const void* g, void* l) {
    __builtin_amdgcn_global_load_lds(
        (const __attribute__((address_space(1))) void*)g,
        (__attribute__((address_space(3))) void*)l, 16, 0, 0);
}

// ---------------- cast fp32 -> bf16 (vectorized x4, optional scale) ----------------
__global__ void cast_bf16_k(const float* __restrict__ src, unsigned short* __restrict__ dst,
                            int n4, float scale) {
    int i = blockIdx.x * blockDim.x + threadIdx.x;
    if (i < n4) {
        float4 v = ((const float4*)src)[i];
        ushort4 o;
        o.x = f2b(v.x * scale); o.y = f2b(v.y * scale);
        o.z = f2b(v.z * scale); o.w = f2b(v.w * scale);
        ((ushort4*)dst)[i] = o;
    }
}

// ---------------- RMSNorm fp32 -> bf16, D=1024, one block per row ----------------
__global__ void rmsnorm_bf16_k(const float* __restrict__ x, const float* __restrict__ g,
                               unsigned short* __restrict__ out) {
    int row = blockIdx.x;
    int t = threadIdx.x;  // 256
    const float4* xr = (const float4*)(x + (size_t)row * 1024);
    float4 xv = xr[t];
    float ss = xv.x * xv.x + xv.y * xv.y + xv.z * xv.z + xv.w * xv.w;
    #pragma unroll
    for (int off = 32; off; off >>= 1) ss += __shfl_xor(ss, off, 64);
    __shared__ float red[4];
    int wave = t >> 6, lane = t & 63;
    if (lane == 0) red[wave] = ss;
    __syncthreads();
    float tot = red[0] + red[1] + red[2] + red[3];
    float rn = rsqrtf(tot * (1.0f / 1024.0f) + 1e-5f);
    float4 gv = ((const float4*)g)[t];
    ushort4 o4;
    o4.x = f2b(xv.x * rn * gv.x);
    o4.y = f2b(xv.y * rn * gv.y);
    o4.z = f2b(xv.z * rn * gv.z);
    o4.w = f2b(xv.w * rn * gv.w);
    ((ushort4*)out)[(size_t)row * 256 + t] = o4;
}

// ---------------- V transpose: qkv V-part [s][d] -> vt[(bh*64+d)][s] ----------------
__global__ void vtrans_k(const unsigned short* __restrict__ qkv, unsigned short* __restrict__ vt) {
    __shared__ unsigned short Ls[64 * 72];
    int st = blockIdx.x, bh = blockIdx.y, b = bh >> 4, h = bh & 15;
    int s0 = st * 64;
    int tid = threadIdx.x;
    const unsigned short* Vg = qkv + (size_t)(b * 2048 + s0) * 3072 + 2048 + h * 64;
    #pragma unroll
    for (int i = 0; i < 2; i++) {
        int idx = i * 256 + tid;
        int r = idx >> 3, c8 = (idx & 7) * 8;
        *(uint4*)&Ls[r * 72 + c8] = *(const uint4*)&Vg[(size_t)r * 3072 + c8];
    }
    __syncthreads();
    #pragma unroll
    for (int i = 0; i < 2; i++) {
        int idx = i * 256 + tid;
        int d = idx >> 3, s8 = (idx & 7) * 8;
        unsigned short tmp[8];
        #pragma unroll
        for (int j = 0; j < 8; j++) tmp[j] = Ls[(s8 + j) * 72 + d];
        *(uint4*)&vt[(size_t)(bh * 64 + d) * 2048 + s0 + s8] = *(uint4*)tmp;
    }
}

// ---------------- GEMM  C[M,N] = A[M,K] * B[N,K]^T, 128x128 tile ----------------
// EPI: 0 = store bf16, 1 = store fp32 (res + acc), 2 = gelu -> bf16
template <int EPI>
__launch_bounds__(256)
__global__ void gemm_bt(const unsigned short* __restrict__ A, const unsigned short* __restrict__ B,
                        const float* __restrict__ res, void* __restrict__ out,
                        int M, int N, int K) {
    __shared__ __align__(16) unsigned short smem[2 * 128 * 32];  // 16 KB
    unsigned short* As = smem;
    unsigned short* Bs = smem + 128 * 32;

    int tid = threadIdx.x;
    int wave = tid >> 6, lane = tid & 63;
    int lrow = lane & 15, quad = lane >> 4;
    int qx8 = (quad ^ ((lrow >> 1) & 3)) * 8;

    int gx = gridDim.x, gy = gridDim.y;
    int cid = blockIdx.y * gx + blockIdx.x;
    int per = (gx * gy) >> 3;
    int nid = (cid & 7) * per + (cid >> 3);
    const int CG = 8;
    int group = nid / (CG * gy);
    int rem = nid % (CG * gy);
    int bxs = group * CG + (rem % CG);
    int bys = rem / CG;
    int bm = bys * 128, bn = bxs * 128;

    int wm = (wave & 1) * 64, wn = (wave >> 1) * 64;

    const unsigned short* Ab = A + (size_t)bm * K;
    const unsigned short* Bb = B + (size_t)bn * K;

    f32x4 zero = {0.f, 0.f, 0.f, 0.f};
    f32x4 acc[4][4];
    #pragma unroll
    for (int mi = 0; mi < 4; mi++)
        #pragma unroll
        for (int ni = 0; ni < 4; ni++) acc[mi][ni] = zero;

    int wbase = tid & 192;

    for (int k0 = 0; k0 < K; k0 += 32) {
        if (k0) __syncthreads();
        #pragma unroll
        for (int i = 0; i < 2; i++) {
            int idx = i * 256 + tid;
            int r = idx >> 2;
            int c = ((idx & 3) ^ ((idx >> 3) & 3)) * 8;  // swizzled chunk
            gload_lds16(&Ab[(size_t)r * K + k0 + c], As + ((size_t)(i * 256 + wbase)) * 8);
            gload_lds16(&Bb[(size_t)r * K + k0 + c], Bs + ((size_t)(i * 256 + wbase)) * 8);
        }
        __syncthreads();

        bf16x8 af[4], bfr[4];
        #pragma unroll
        for (int mi = 0; mi < 4; mi++)
            af[mi] = *(const bf16x8*)&As[(wm + mi * 16 + lrow) * 32 + qx8];
        #pragma unroll
        for (int ni = 0; ni < 4; ni++)
            bfr[ni] = *(const bf16x8*)&Bs[(wn + ni * 16 + lrow) * 32 + qx8];
        #pragma unroll
        for (int mi = 0; mi < 4; mi++)
            #pragma unroll
            for (int ni = 0; ni < 4; ni++)
                acc[mi][ni] = __builtin_amdgcn_mfma_f32_16x16x32_bf16(af[mi], bfr[ni], acc[mi][ni], 0, 0, 0);
    }

    float* Cs = (float*)smem;
    int row16 = lane >> 2, cseg = (lane & 3) * 16;
    #pragma unroll
    for (int p = 0; p < 4; p++) {
        __syncthreads();
        #pragma unroll
        for (int ni = 0; ni < 4; ni++)
            #pragma unroll
            for (int r = 0; r < 4; r++)
                Cs[wave * 1024 + (quad * 4 + r) * 64 + ni * 16 + lrow] = acc[p][ni][r];
        __syncthreads();
        const float* src = &Cs[wave * 1024 + row16 * 64 + cseg];
        int grow = bm + wm + p * 16 + row16;
        int gcol = bn + wn + cseg;
        size_t off = (size_t)grow * N + gcol;
        if (EPI == 1) {
            float* op = (float*)out + off;
            const float* rp = res + off;
            #pragma unroll
            for (int j = 0; j < 4; j++) {
                float4 v = ((const float4*)src)[j];
                float4 rr = ((const float4*)rp)[j];
                v.x += rr.x; v.y += rr.y; v.z += rr.z; v.w += rr.w;
                ((float4*)op)[j] = v;
            }
        } else {
            unsigned short tmp[16];
            #pragma unroll
            for (int j = 0; j < 16; j++) {
                float v = src[j];
                if (EPI == 2) v = gelu_erf(v);
                tmp[j] = f2b(v);
            }
            unsigned short* op = (unsigned short*)out + off;
            *(uint4*)op = *(uint4*)tmp;
            *(uint4*)(op + 8) = *(uint4*)(tmp + 8);
        }
    }
}

// ---------------- GEMM 128x64 tile (N=1024: 512 blocks) ----------------
__launch_bounds__(256)
__global__ void gemm_bt64(const unsigned short* __restrict__ A, const unsigned short* __restrict__ B,
                          const float* __restrict__ res, float* __restrict__ out,
                          int M, int N, int K) {
    __shared__ __align__(16) unsigned short As[128 * 32];  // 8KB
    __shared__ __align__(16) unsigned short Bs[64 * 32];   // 4KB

    int tid = threadIdx.x, wave = tid >> 6, lane = tid & 63;
    int lrow = lane & 15, quad = lane >> 4;
    int qx8 = (quad ^ ((lrow >> 1) & 3)) * 8;

    int gx = gridDim.x, gy = gridDim.y;
    int cid = blockIdx.y * gx + blockIdx.x;
    int per = (gx * gy) >> 3;
    int nid = (cid & 7) * per + (cid >> 3);
    const int CG = 8;
    int group = nid / (CG * gy);
    int rem = nid % (CG * gy);
    int bxs = group * CG + (rem % CG);
    int bys = rem / CG;
    int bm = bys * 128, bn = bxs * 64;

    int wm = (wave & 1) * 64, wn = (wave >> 1) * 32;

    f32x4 zero = {0.f, 0.f, 0.f, 0.f};
    f32x4 acc[4][2];
    #pragma unroll
    for (int mi = 0; mi < 4; mi++)
        #pragma unroll
        for (int ni = 0; ni < 2; ni++) acc[mi][ni] = zero;

    int rr4 = lane >> 2;
    int c8s = ((lane & 3) ^ ((lane >> 3) & 3)) * 8;
    const unsigned short* Ab = A + (size_t)(bm + wave * 32 + rr4) * K + c8s;
    const unsigned short* Bb = B + (size_t)(bn + wave * 16 + rr4) * K + c8s;

    for (int k0 = 0; k0 < K; k0 += 32) {
        if (k0) __syncthreads();
        gload_lds16(Ab + k0, &As[(wave * 32) * 32]);
        gload_lds16(Ab + (size_t)16 * K + k0, &As[(wave * 32 + 16) * 32]);
        gload_lds16(Bb + k0, &Bs[(wave * 16) * 32]);
        __syncthreads();

        bf16x8 af[4], bfr[2];
        #pragma unroll
        for (int mi = 0; mi < 4; mi++)
            af[mi] = *(const bf16x8*)&As[(wm + mi * 16 + lrow) * 32 + qx8];
        #pragma unroll
        for (int ni = 0; ni < 2; ni++)
            bfr[ni] = *(const bf16x8*)&Bs[(wn + ni * 16 + lrow) * 32 + qx8];
        #pragma unroll
        for (int mi = 0; mi < 4; mi++)
            #pragma unroll
            for (int ni = 0; ni < 2; ni++)
                acc[mi][ni] = __builtin_amdgcn_mfma_f32_16x16x32_bf16(af[mi], bfr[ni], acc[mi][ni], 0, 0, 0);
    }

    float* Cs = (float*)As;
    int row16 = lane >> 2, cseg = (lane & 3) * 8;
    #pragma unroll
    for (int p = 0; p < 4; p++) {
        __syncthreads();
        #pragma unroll
        for (int ni = 0; ni < 2; ni++)
            #pragma unroll
            for (int r = 0; r < 4; r++)
                Cs[wave * 512 + (quad * 4 + r) * 32 + ni * 16 + lrow] = acc[p][ni][r];
        __syncthreads();
        const float* src = &Cs[wave * 512 + row16 * 32 + cseg];
        int grow = bm + wm + p * 16 + row16;
        int gcol = bn + wn + cseg;
        size_t off = (size_t)grow * N + gcol;
        float* op = out + off;
        const float* rp = res + off;
        #pragma unroll
        for (int j = 0; j < 2; j++) {
            float4 v = ((const float4*)src)[j];
            float4 rv = ((const float4*)rp)[j];
            v.x += rv.x; v.y += rv.y; v.z += rv.z; v.w += rv.w;
            ((float4*)op)[j] = v;
        }
    }
}

// ---------------- Flash attention, causal, DK=64, balanced q-tile pairs ----------------
// grid (8,32) = 256 blocks = 1/CU. Block handles q-tiles {bx, 15-bx} (128q each):
// (2bx+2) + (32-2bx) = 34 k-tile iters for EVERY block -> perfect balance, no tail.
// K/V staged via global_load_lds (double-buffered, 1 barrier/iter, prefetch-1).
// S^T MFMA form (round-5-verified): s = mfma(K_frag, Q_frag); P-write = 4x ds_write_b64.
// Fixed-max softmax (scale folded into wq cast). XCD remap: XCD x hosts bh {4x..4x+3}
// -> 2MB K/V working set per XCD L2.
__launch_bounds__(256)
__global__ void attn_k(const unsigned short* __restrict__ qkv,
                       const unsigned short* __restrict__ vt,
                       unsigned short* __restrict__ attn_out) {
    const int ROWQKV = 3072;
    int cid = (int)(blockIdx.y * gridDim.x + blockIdx.x);  // gridDim.x == 8
    int bh = (cid & 7) * 4 + (cid >> 6);
    int bx = (cid >> 3) & 7;
    int b = bh >> 4, h = bh & 15;
    int qtA = bx, qtB = 15 - bx;
    int nktA = 2 * qtA + 2, nktB = 2 * qtB + 2;
    int ntot = nktA + nktB;  // 34 for all blocks

    __shared__ __align__(16) unsigned short Ks[2][2][64 * 32];  // 16 KB
    __shared__ __align__(16) unsigned short Vs[2][2][64 * 32];  // 16 KB
    __shared__ __align__(16) unsigned short Ps[8][16 * 72];     // 18 KB

    int tid = threadIdx.x, wave = tid >> 6, lane = tid & 63;
    int lrow = lane & 15, quad = lane >> 4;
    int rr4 = lane >> 2;
    int c8s = ((lane & 3) ^ ((lane >> 3) & 3)) * 8;
    int qx8 = (quad ^ ((lrow >> 1) & 3)) * 8;

    size_t base = (size_t)b * 2048 * ROWQKV;

    // Q B-fragments for both phases x 2 strips x 2 halves (query = q0+strip*64+wave*16+lrow)
    bf16x8 qf[2][2][2];
    #pragma unroll
    for (int p = 0; p < 2; p++) {
        int q0 = (p ? qtB : qtA) * 128;
        #pragma unroll
        for (int s = 0; s < 2; s++) {
            const unsigned short* Qg = qkv + base +
                (size_t)(q0 + s * 64 + wave * 16 + lrow) * ROWQKV + h * 64 + quad * 8;
            qf[p][s][0] = *(const bf16x8*)Qg;
            qf[p][s][1] = *(const bf16x8*)(Qg + 32);
        }
    }

    const unsigned short* Kg0 = qkv + base + (size_t)(wave * 16 + rr4) * ROWQKV + 1024 + h * 64 + c8s;
    const unsigned short* Vg0 = vt + (size_t)(bh * 64 + wave * 16 + rr4) * 2048 + c8s;

    auto stage = [&](int t, int nb) {
        const unsigned short* Kg = Kg0 + (size_t)(t * 64) * ROWQKV;
        const unsigned short* Vg = Vg0 + t * 64;
        gload_lds16(Kg,      &Ks[nb][0][wave * 16 * 32]);
        gload_lds16(Kg + 32, &Ks[nb][1][wave * 16 * 32]);
        gload_lds16(Vg,      &Vs[nb][0][wave * 16 * 32]);
        gload_lds16(Vg + 32, &Vs[nb][1][wave * 16 * 32]);
    };

    f32x4 zero = {0.f, 0.f, 0.f, 0.f};
    f32x4 oA[4], oB[4];
    float lA = 0.f, lB = 0.f;
    #pragma unroll
    for (int ni = 0; ni < 4; ni++) { oA[ni] = zero; oB[ni] = zero; }

    int qloc = wave * 16 + lrow;  // query index local to a 64-strip

    // per-strip tile step: S^T = K Q^T, fixed-max exp2, P via wave-private LDS, O += P V
    auto process = [&](bf16x8 q0f, bf16x8 q1f, f32x4* o, float& l,
                       unsigned short* Pw, bool diag, int buf) {
        f32x4 s[4];
        #pragma unroll
        for (int ni = 0; ni < 4; ni++) s[ni] = zero;
        #pragma unroll
        for (int ni = 0; ni < 4; ni++) {
            bf16x8 kf = *(const bf16x8*)&Ks[buf][0][(ni * 16 + lrow) * 32 + qx8];
            s[ni] = __builtin_amdgcn_mfma_f32_16x16x32_bf16(kf, q0f, s[ni], 0, 0, 0);
        }
        #pragma unroll
        for (int ni = 0; ni < 4; ni++) {
            bf16x8 kf = *(const bf16x8*)&Ks[buf][1][(ni * 16 + lrow) * 32 + qx8];
            s[ni] = __builtin_amdgcn_mfma_f32_16x16x32_bf16(kf, q1f, s[ni], 0, 0, 0);
        }
        // lane holds S[key = ni*16 + quad*4 + r][query = lrow]
        if (diag) {
            #pragma unroll
            for (int ni = 0; ni < 4; ni++)
                #pragma unroll
                for (int r = 0; r < 4; r++) {
                    float p = exp2f(s[ni][r]);
                    if (ni * 16 + quad * 4 + r > qloc) p = 0.f;
                    s[ni][r] = p;
                    l += p;
                }
        } else {
            #pragma unroll
            for (int ni = 0; ni < 4; ni++)
                #pragma unroll
                for (int r = 0; r < 4; r++) {
                    float p = exp2f(s[ni][r]);
                    s[ni][r] = p;
                    l += p;
                }
        }
        #pragma unroll
        for (int ni = 0; ni < 4; ni++) {
            uint2 pk;
            pk.x = (unsigned int)f2b(s[ni][0]) | ((unsigned int)f2b(s[ni][1]) << 16);
            pk.y = (unsigned int)f2b(s[ni][2]) | ((unsigned int)f2b(s[ni][3]) << 16);
            *(uint2*)&Pw[lrow * 72 + ni * 16 + quad * 4] = pk;
        }
        bf16x8 p0 = *(const bf16x8*)&Pw[lrow * 72 + quad * 8];
        bf16x8 p1 = *(const bf16x8*)&Pw[lrow * 72 + 32 + quad * 8];
        #pragma unroll
        for (int ni = 0; ni < 4; ni++) {
            bf16x8 vf = *(const bf16x8*)&Vs[buf][0][(ni * 16 + lrow) * 32 + qx8];
            o[ni] = __builtin_amdgcn_mfma_f32_16x16x32_bf16(p0, vf, o[ni], 0, 0, 0);
        }
        #pragma unroll
        for (int ni = 0; ni < 4; ni++) {
            bf16x8 vf = *(const bf16x8*)&Vs[buf][1][(ni * 16 + lrow) * 32 + qx8];
            o[ni] = __builtin_amdgcn_mfma_f32_16x16x32_bf16(p1, vf, o[ni], 0, 0, 0);
        }
    };

    auto epilogue = [&](int qbase) {
        float la = lA, lb = lB;
        la += __shfl_xor(la, 16, 64); la += __shfl_xor(la, 32, 64);
        lb += __shfl_xor(lb, 16, 64); lb += __shfl_xor(lb, 32, 64);
        #pragma unroll
        for (int strip = 0; strip < 2; strip++) {
            f32x4* o = strip ? oB : oA;
            float lv = strip ? lb : la;
            #pragma unroll
            for (int r = 0; r < 4; r++) {
                float lr = __shfl(lv, quad * 4 + r, 64);
                float inv = 1.0f / lr;
                int q = qbase + strip * 64 + wave * 16 + quad * 4 + r;
                #pragma unroll
                for (int ni = 0; ni < 4; ni++)
                    attn_out[((size_t)b * 2048 + q) * 1024 + h * 64 + ni * 16 + lrow] =
                        f2b(o[ni][r] * inv);
            }
        }
    };

    // prologue: stage phase-1 tile 0 into buf 0
    stage(0, 0);

    for (int j = 0; j < ntot; j++) {
        __syncthreads();  // barrier drains vmcnt: tile j staged, buf (j+1)&1 free
        if (j + 1 < ntot) {
            int t = (j + 1 < nktA) ? (j + 1) : (j + 1 - nktA);
            stage(t, (j + 1) & 1);
        }
        int buf = j & 1;
        if (j < nktA) {
            if (j < nktA - 1)
                process(qf[0][0][0], qf[0][0][1], oA, lA, Ps[wave], j == nktA - 2, buf);
            process(qf[0][1][0], qf[0][1][1], oB, lB, Ps[wave + 4], j == nktA - 1, buf);
            if (j == nktA - 1) {
                epilogue(qtA * 128);
                #pragma unroll
                for (int ni = 0; ni < 4; ni++) { oA[ni] = zero; oB[ni] = zero; }
                lA = 0.f; lB = 0.f;
            }
        } else {
            int t = j - nktA;
            if (t < nktB - 1)
                process(qf[1][0][0], qf[1][0][1], oA, lA, Ps[wave], t == nktB - 2, buf);
            process(qf[1][1][0], qf[1][1][1], oB, lB, Ps[wave + 4], t == nktB - 1, buf);
        }
    }
    epilogue(qtB * 128);
}

extern "C" void kernel_launch(void* const* d_in, const int* in_sizes, int n_in,
                              void* d_out, int out_size, void* d_ws, size_t ws_size,
                              hipStream_t stream) {
    const float* x  = (const float*)d_in[0];
    const float* g1 = (const float*)d_in[1];
    const float* g2 = (const float*)d_in[2];
    const float* wq = (const float*)d_in[3];
    const float* wk = (const float*)d_in[4];
    const float* wv = (const float*)d_in[5];
    const float* wo = (const float*)d_in[6];
    const float* w1 = (const float*)d_in[7];
    const float* w2 = (const float*)d_in[8];
    float* out = (float*)d_out;

    const size_t BS = 4096;
    const size_t D = 1024, DFF = 4096;
    const float QSCALE = 0.18033688011112042f;  // 0.125 * log2(e), folded into wq

    char* w = (char*)d_ws;
    unsigned short* xn_b   = (unsigned short*)w; w += BS * D * 2;
    unsigned short* wqkv_b = (unsigned short*)w; w += 3 * D * D * 2;
    unsigned short* qkv_b  = (unsigned short*)w; w += BS * 3 * D * 2;
    unsigned short* vt_b   = (unsigned short*)w; w += BS * D * 2;
    unsigned short* attn_b = (unsigned short*)w; w += BS * D * 2;
    unsigned short* wo_b   = (unsigned short*)w; w += D * D * 2;
    float*          x2     = (float*)w;          w += BS * D * 4;
    unsigned short* xn2_b  = (unsigned short*)w; w += BS * D * 2;
    unsigned short* w1_b   = (unsigned short*)w; w += DFF * D * 2;
    unsigned short* h_b    = (unsigned short*)w; w += BS * DFF * 2;
    unsigned short* w2_b   = (unsigned short*)w; w += D * DFF * 2;

    int nW = (int)(D * D / 4);
    cast_bf16_k<<<(nW + 255) / 256, 256, 0, stream>>>(wq, wqkv_b, nW, QSCALE);
    cast_bf16_k<<<(nW + 255) / 256, 256, 0, stream>>>(wk, wqkv_b + D * D, nW, 1.0f);
    cast_bf16_k<<<(nW + 255) / 256, 256, 0, stream>>>(wv, wqkv_b + 2 * D * D, nW, 1.0f);
    cast_bf16_k<<<(nW + 255) / 256, 256, 0, stream>>>(wo, wo_b, nW, 1.0f);
    int nF = (int)(DFF * D / 4);
    cast_bf16_k<<<(nF + 255) / 256, 256, 0, stream>>>(w1, w1_b, nF, 1.0f);
    cast_bf16_k<<<(nF + 255) / 256, 256, 0, stream>>>(w2, w2_b, nF, 1.0f);

    rmsnorm_bf16_k<<<(int)BS, 256, 0, stream>>>(x, g1, xn_b);

    // qkv = xn @ [wq;wk;wv]^T   [4096 x 3072]
    gemm_bt<0><<<dim3(24, 32), 256, 0, stream>>>(xn_b, wqkv_b, nullptr, qkv_b, 4096, 3072, 1024);

    // V transpose for attention B-frags
    vtrans_k<<<dim3(32, 32), 256, 0, stream>>>(qkv_b, vt_b);

    // causal flash attention (balanced q-tile pairs, 256 blocks)
    attn_k<<<dim3(8, 32), 256, 0, stream>>>(qkv_b, vt_b, attn_b);

    // x2 = x + attn @ wo^T
    gemm_bt64<<<dim3(16, 32), 256, 0, stream>>>(attn_b, wo_b, x, x2, 4096, 1024, 1024);

    rmsnorm_bf16_k<<<(int)BS, 256, 0, stream>>>(x2, g2, xn2_b);

    // h = gelu(xn2 @ w1^T)   [4096 x 4096]
    gemm_bt<2><<<dim3(32, 32), 256, 0, stream>>>(xn2_b, w1_b, nullptr, h_b, 4096, 4096, 1024);

    // out = x2 + h @ w2^T
    gemm_bt64<<<dim3(16, 32), 256, 0, stream>>>(h_b, w2_b, x2, out, 4096, 1024, 4096);
}

// Round 8
// 373.641 us; speedup vs baseline: 1.4384x; 1.0140x over previous
//
#include <hip/hip_runtime.h>
#include <hip/hip_bf16.h>

typedef __attribute__((ext_vector_type(8))) short bf16x8;
typedef __attribute__((ext_vector_type(4))) float f32x4;

__device__ __forceinline__ unsigned short f2b(float f) {
    unsigned int u = __float_as_uint(f);
    unsigned int r = u + 0x7FFFu + ((u >> 16) & 1u);
    return (unsigned short)(r >> 16);
}

__device__ __forceinline__ float gelu_erf(float v) {
    return 0.5f * v * (1.0f + erff(v * 0.70710678118654752f));
}

// async global->LDS, 16B per lane. LDS dest must be wave-uniform; HW adds lane*16.
__device__ __forceinline__ void gload_lds16(const void* g, void* l) {
    __builtin_amdgcn_global_load_lds(
        (const __attribute__((address_space(1))) void*)g,
        (__attribute__((address_space(3))) void*)l, 16, 0, 0);
}

// ---------------- fused weight cast: all 6 weights in one launch ----------------
// segments (float4 units): wq,wk,wv,wo = S=262144 each; w1,w2 = F=1048576 each.
// dst offsets are in SHORTS: wk at D*D = 4*S shorts, wv at 2*D*D = 8*S... NO:
// D*D elements = 4*S shorts?  D*D = 1048576 elements; S float4 units = 4*S floats.
// 4*S = 1048576 = D*D.  So wk starts at short index S*4, wv at short index 2*S*4.
__global__ void cast_all_k(const float* __restrict__ wq, const float* __restrict__ wk,
                           const float* __restrict__ wv, const float* __restrict__ wo,
                           const float* __restrict__ w1, const float* __restrict__ w2,
                           unsigned short* __restrict__ wqkv_b, unsigned short* __restrict__ wo_b,
                           unsigned short* __restrict__ w1_b, unsigned short* __restrict__ w2_b,
                           float qscale) {
    const int S = 262144, F = 1048576;
    int i = blockIdx.x * blockDim.x + threadIdx.x;
    const float* src; unsigned short* dst; int off; float scale = 1.0f;
    if (i < S)              { src = wq; dst = wqkv_b;             off = i;          scale = qscale; }
    else if (i < 2 * S)     { src = wk; dst = wqkv_b + S * 4;     off = i - S; }      // +D*D shorts
    else if (i < 3 * S)     { src = wv; dst = wqkv_b + 2 * S * 4; off = i - 2 * S; }  // +2*D*D shorts
    else if (i < 4 * S)     { src = wo; dst = wo_b;               off = i - 3 * S; }
    else if (i < 4 * S + F) { src = w1; dst = w1_b;               off = i - 4 * S; }
    else                    { src = w2; dst = w2_b;               off = i - 4 * S - F; }
    float4 v = ((const float4*)src)[off];
    ushort4 o;
    o.x = f2b(v.x * scale); o.y = f2b(v.y * scale);
    o.z = f2b(v.z * scale); o.w = f2b(v.w * scale);
    ((ushort4*)(dst))[off] = o;
}

// ---------------- RMSNorm fp32 -> bf16, D=1024, one block per row ----------------
__global__ void rmsnorm_bf16_k(const float* __restrict__ x, const float* __restrict__ g,
                               unsigned short* __restrict__ out) {
    int row = blockIdx.x;
    int t = threadIdx.x;  // 256
    const float4* xr = (const float4*)(x + (size_t)row * 1024);
    float4 xv = xr[t];
    float ss = xv.x * xv.x + xv.y * xv.y + xv.z * xv.z + xv.w * xv.w;
    #pragma unroll
    for (int off = 32; off; off >>= 1) ss += __shfl_xor(ss, off, 64);
    __shared__ float red[4];
    int wave = t >> 6, lane = t & 63;
    if (lane == 0) red[wave] = ss;
    __syncthreads();
    float tot = red[0] + red[1] + red[2] + red[3];
    float rn = rsqrtf(tot * (1.0f / 1024.0f) + 1e-5f);
    float4 gv = ((const float4*)g)[t];
    ushort4 o4;
    o4.x = f2b(xv.x * rn * gv.x);
    o4.y = f2b(xv.y * rn * gv.y);
    o4.z = f2b(xv.z * rn * gv.z);
    o4.w = f2b(xv.w * rn * gv.w);
    ((ushort4*)out)[(size_t)row * 256 + t] = o4;
}

// ---------------- V transpose: qkv V-part [s][d] -> vt[(bh*64+d)][s] ----------------
__global__ void vtrans_k(const unsigned short* __restrict__ qkv, unsigned short* __restrict__ vt) {
    __shared__ unsigned short Ls[64 * 72];
    int st = blockIdx.x, bh = blockIdx.y, b = bh >> 4, h = bh & 15;
    int s0 = st * 64;
    int tid = threadIdx.x;
    const unsigned short* Vg = qkv + (size_t)(b * 2048 + s0) * 3072 + 2048 + h * 64;
    #pragma unroll
    for (int i = 0; i < 2; i++) {
        int idx = i * 256 + tid;
        int r = idx >> 3, c8 = (idx & 7) * 8;
        *(uint4*)&Ls[r * 72 + c8] = *(const uint4*)&Vg[(size_t)r * 3072 + c8];
    }
    __syncthreads();
    #pragma unroll
    for (int i = 0; i < 2; i++) {
        int idx = i * 256 + tid;
        int d = idx >> 3, s8 = (idx & 7) * 8;
        unsigned short tmp[8];
        #pragma unroll
        for (int j = 0; j < 8; j++) tmp[j] = Ls[(s8 + j) * 72 + d];
        *(uint4*)&vt[(size_t)(bh * 64 + d) * 2048 + s0 + s8] = *(uint4*)tmp;
    }
}

// ---------------- GEMM  C[M,N] = A[M,K] * B[N,K]^T, 128x128 tile ----------------
// EPI: 0 = store bf16, 1 = store fp32 (res + acc), 2 = gelu -> bf16
template <int EPI>
__launch_bounds__(256)
__global__ void gemm_bt(const unsigned short* __restrict__ A, const unsigned short* __restrict__ B,
                        const float* __restrict__ res, void* __restrict__ out,
                        int M, int N, int K) {
    __shared__ __align__(16) unsigned short smem[2 * 128 * 32];  // 16 KB
    unsigned short* As = smem;
    unsigned short* Bs = smem + 128 * 32;

    int tid = threadIdx.x;
    int wave = tid >> 6, lane = tid & 63;
    int lrow = lane & 15, quad = lane >> 4;
    int qx8 = (quad ^ ((lrow >> 1) & 3)) * 8;

    int gx = gridDim.x, gy = gridDim.y;
    int cid = blockIdx.y * gx + blockIdx.x;
    int per = (gx * gy) >> 3;
    int nid = (cid & 7) * per + (cid >> 3);
    const int CG = 8;
    int group = nid / (CG * gy);
    int rem = nid % (CG * gy);
    int bxs = group * CG + (rem % CG);
    int bys = rem / CG;
    int bm = bys * 128, bn = bxs * 128;

    int wm = (wave & 1) * 64, wn = (wave >> 1) * 64;

    const unsigned short* Ab = A + (size_t)bm * K;
    const unsigned short* Bb = B + (size_t)bn * K;

    f32x4 zero = {0.f, 0.f, 0.f, 0.f};
    f32x4 acc[4][4];
    #pragma unroll
    for (int mi = 0; mi < 4; mi++)
        #pragma unroll
        for (int ni = 0; ni < 4; ni++) acc[mi][ni] = zero;

    int wbase = tid & 192;

    for (int k0 = 0; k0 < K; k0 += 32) {
        if (k0) __syncthreads();
        #pragma unroll
        for (int i = 0; i < 2; i++) {
            int idx = i * 256 + tid;
            int r = idx >> 2;
            int c = ((idx & 3) ^ ((idx >> 3) & 3)) * 8;  // swizzled chunk
            gload_lds16(&Ab[(size_t)r * K + k0 + c], As + ((size_t)(i * 256 + wbase)) * 8);
            gload_lds16(&Bb[(size_t)r * K + k0 + c], Bs + ((size_t)(i * 256 + wbase)) * 8);
        }
        __syncthreads();

        bf16x8 af[4], bfr[4];
        #pragma unroll
        for (int mi = 0; mi < 4; mi++)
            af[mi] = *(const bf16x8*)&As[(wm + mi * 16 + lrow) * 32 + qx8];
        #pragma unroll
        for (int ni = 0; ni < 4; ni++)
            bfr[ni] = *(const bf16x8*)&Bs[(wn + ni * 16 + lrow) * 32 + qx8];
        #pragma unroll
        for (int mi = 0; mi < 4; mi++)
            #pragma unroll
            for (int ni = 0; ni < 4; ni++)
                acc[mi][ni] = __builtin_amdgcn_mfma_f32_16x16x32_bf16(af[mi], bfr[ni], acc[mi][ni], 0, 0, 0);
    }

    float* Cs = (float*)smem;
    int row16 = lane >> 2, cseg = (lane & 3) * 16;
    #pragma unroll
    for (int p = 0; p < 4; p++) {
        __syncthreads();
        #pragma unroll
        for (int ni = 0; ni < 4; ni++)
            #pragma unroll
            for (int r = 0; r < 4; r++)
                Cs[wave * 1024 + (quad * 4 + r) * 64 + ni * 16 + lrow] = acc[p][ni][r];
        __syncthreads();
        const float* src = &Cs[wave * 1024 + row16 * 64 + cseg];
        int grow = bm + wm + p * 16 + row16;
        int gcol = bn + wn + cseg;
        size_t off = (size_t)grow * N + gcol;
        if (EPI == 1) {
            float* op = (float*)out + off;
            const float* rp = res + off;
            #pragma unroll
            for (int j = 0; j < 4; j++) {
                float4 v = ((const float4*)src)[j];
                float4 rr = ((const float4*)rp)[j];
                v.x += rr.x; v.y += rr.y; v.z += rr.z; v.w += rr.w;
                ((float4*)op)[j] = v;
            }
        } else {
            unsigned short tmp[16];
            #pragma unroll
            for (int j = 0; j < 16; j++) {
                float v = src[j];
                if (EPI == 2) v = gelu_erf(v);
                tmp[j] = f2b(v);
            }
            unsigned short* op = (unsigned short*)out + off;
            *(uint4*)op = *(uint4*)tmp;
            *(uint4*)(op + 8) = *(uint4*)(tmp + 8);
        }
    }
}

// ---------------- GEMM 128x64 tile, DOUBLE-BUFFERED prefetch (N=1024: 512 blocks) ----------------
// Prefetch distance = 1 full k-iter: stage(k+1) issued right after the barrier that
// publishes tile k, so its latency overlaps tile k's MFMA. 1 barrier/iter.
__launch_bounds__(256)
__global__ void gemm_bt64(const unsigned short* __restrict__ A, const unsigned short* __restrict__ B,
                          const float* __restrict__ res, float* __restrict__ out,
                          int M, int N, int K) {
    __shared__ __align__(16) unsigned short As[2][128 * 32];  // 16KB
    __shared__ __align__(16) unsigned short Bs[2][64 * 32];   // 8KB

    int tid = threadIdx.x, wave = tid >> 6, lane = tid & 63;
    int lrow = lane & 15, quad = lane >> 4;
    int qx8 = (quad ^ ((lrow >> 1) & 3)) * 8;

    int gx = gridDim.x, gy = gridDim.y;
    int cid = blockIdx.y * gx + blockIdx.x;
    int per = (gx * gy) >> 3;
    int nid = (cid & 7) * per + (cid >> 3);
    const int CG = 8;
    int group = nid / (CG * gy);
    int rem = nid % (CG * gy);
    int bxs = group * CG + (rem % CG);
    int bys = rem / CG;
    int bm = bys * 128, bn = bxs * 64;

    int wm = (wave & 1) * 64, wn = (wave >> 1) * 32;

    f32x4 zero = {0.f, 0.f, 0.f, 0.f};
    f32x4 acc[4][2];
    #pragma unroll
    for (int mi = 0; mi < 4; mi++)
        #pragma unroll
        for (int ni = 0; ni < 2; ni++) acc[mi][ni] = zero;

    int rr4 = lane >> 2;
    int c8s = ((lane & 3) ^ ((lane >> 3) & 3)) * 8;
    const unsigned short* Ab = A + (size_t)(bm + wave * 32 + rr4) * K + c8s;
    const unsigned short* Bb = B + (size_t)(bn + wave * 16 + rr4) * K + c8s;

    auto stage = [&](int k0, int nb) {
        gload_lds16(Ab + k0, &As[nb][(wave * 32) * 32]);
        gload_lds16(Ab + (size_t)16 * K + k0, &As[nb][(wave * 32 + 16) * 32]);
        gload_lds16(Bb + k0, &Bs[nb][(wave * 16) * 32]);
    };

    int nIter = K >> 5;
    stage(0, 0);
    for (int it = 0; it < nIter; it++) {
        __syncthreads();  // tile 'it' staged (its loads issued before this barrier)
        if (it + 1 < nIter) stage((it + 1) * 32, (it + 1) & 1);
        int buf = it & 1;

        bf16x8 af[4], bfr[2];
        #pragma unroll
        for (int mi = 0; mi < 4; mi++)
            af[mi] = *(const bf16x8*)&As[buf][(wm + mi * 16 + lrow) * 32 + qx8];
        #pragma unroll
        for (int ni = 0; ni < 2; ni++)
            bfr[ni] = *(const bf16x8*)&Bs[buf][(wn + ni * 16 + lrow) * 32 + qx8];
        #pragma unroll
        for (int mi = 0; mi < 4; mi++)
            #pragma unroll
            for (int ni = 0; ni < 2; ni++)
                acc[mi][ni] = __builtin_amdgcn_mfma_f32_16x16x32_bf16(af[mi], bfr[ni], acc[mi][ni], 0, 0, 0);
    }

    float* Cs = (float*)As[0];
    int row16 = lane >> 2, cseg = (lane & 3) * 8;
    #pragma unroll
    for (int p = 0; p < 4; p++) {
        __syncthreads();
        #pragma unroll
        for (int ni = 0; ni < 2; ni++)
            #pragma unroll
            for (int r = 0; r < 4; r++)
                Cs[wave * 512 + (quad * 4 + r) * 32 + ni * 16 + lrow] = acc[p][ni][r];
        __syncthreads();
        const float* src = &Cs[wave * 512 + row16 * 32 + cseg];
        int grow = bm + wm + p * 16 + row16;
        int gcol = bn + wn + cseg;
        size_t off = (size_t)grow * N + gcol;
        float* op = out + off;
        const float* rp = res + off;
        #pragma unroll
        for (int j = 0; j < 2; j++) {
            float4 v = ((const float4*)src)[j];
            float4 rv = ((const float4*)rp)[j];
            v.x += rv.x; v.y += rv.y; v.z += rv.z; v.w += rv.w;
            ((float4*)op)[j] = v;
        }
    }
}

// ---------------- Flash attention, causal, DK=64, balanced q-tile pairs ----------------
__launch_bounds__(256)
__global__ void attn_k(const unsigned short* __restrict__ qkv,
                       const unsigned short* __restrict__ vt,
                       unsigned short* __restrict__ attn_out) {
    const int ROWQKV = 3072;
    int cid = (int)(blockIdx.y * gridDim.x + blockIdx.x);  // gridDim.x == 8
    int bh = (cid & 7) * 4 + (cid >> 6);
    int bx = (cid >> 3) & 7;
    int b = bh >> 4, h = bh & 15;
    int qtA = bx, qtB = 15 - bx;
    int nktA = 2 * qtA + 2, nktB = 2 * qtB + 2;
    int ntot = nktA + nktB;  // 34 for all blocks

    __shared__ __align__(16) unsigned short Ks[2][2][64 * 32];  // 16 KB
    __shared__ __align__(16) unsigned short Vs[2][2][64 * 32];  // 16 KB
    __shared__ __align__(16) unsigned short Ps[8][16 * 72];     // 18 KB

    int tid = threadIdx.x, wave = tid >> 6, lane = tid & 63;
    int lrow = lane & 15, quad = lane >> 4;
    int rr4 = lane >> 2;
    int c8s = ((lane & 3) ^ ((lane >> 3) & 3)) * 8;
    int qx8 = (quad ^ ((lrow >> 1) & 3)) * 8;

    size_t base = (size_t)b * 2048 * ROWQKV;

    bf16x8 qf[2][2][2];
    #pragma unroll
    for (int p = 0; p < 2; p++) {
        int q0 = (p ? qtB : qtA) * 128;
        #pragma unroll
        for (int s = 0; s < 2; s++) {
            const unsigned short* Qg = qkv + base +
                (size_t)(q0 + s * 64 + wave * 16 + lrow) * ROWQKV + h * 64 + quad * 8;
            qf[p][s][0] = *(const bf16x8*)Qg;
            qf[p][s][1] = *(const bf16x8*)(Qg + 32);
        }
    }

    const unsigned short* Kg0 = qkv + base + (size_t)(wave * 16 + rr4) * ROWQKV + 1024 + h * 64 + c8s;
    const unsigned short* Vg0 = vt + (size_t)(bh * 64 + wave * 16 + rr4) * 2048 + c8s;

    auto stage = [&](int t, int nb) {
        const unsigned short* Kg = Kg0 + (size_t)(t * 64) * ROWQKV;
        const unsigned short* Vg = Vg0 + t * 64;
        gload_lds16(Kg,      &Ks[nb][0][wave * 16 * 32]);
        gload_lds16(Kg + 32, &Ks[nb][1][wave * 16 * 32]);
        gload_lds16(Vg,      &Vs[nb][0][wave * 16 * 32]);
        gload_lds16(Vg + 32, &Vs[nb][1][wave * 16 * 32]);
    };

    f32x4 zero = {0.f, 0.f, 0.f, 0.f};
    f32x4 oA[4], oB[4];
    float lA = 0.f, lB = 0.f;
    #pragma unroll
    for (int ni = 0; ni < 4; ni++) { oA[ni] = zero; oB[ni] = zero; }

    int qloc = wave * 16 + lrow;

    auto process = [&](bf16x8 q0f, bf16x8 q1f, f32x4* o, float& l,
                       unsigned short* Pw, bool diag, int buf) {
        f32x4 s[4];
        #pragma unroll
        for (int ni = 0; ni < 4; ni++) s[ni] = zero;
        #pragma unroll
        for (int ni = 0; ni < 4; ni++) {
            bf16x8 kf = *(const bf16x8*)&Ks[buf][0][(ni * 16 + lrow) * 32 + qx8];
            s[ni] = __builtin_amdgcn_mfma_f32_16x16x32_bf16(kf, q0f, s[ni], 0, 0, 0);
        }
        #pragma unroll
        for (int ni = 0; ni < 4; ni++) {
            bf16x8 kf = *(const bf16x8*)&Ks[buf][1][(ni * 16 + lrow) * 32 + qx8];
            s[ni] = __builtin_amdgcn_mfma_f32_16x16x32_bf16(kf, q1f, s[ni], 0, 0, 0);
        }
        if (diag) {
            #pragma unroll
            for (int ni = 0; ni < 4; ni++)
                #pragma unroll
                for (int r = 0; r < 4; r++) {
                    float p = exp2f(s[ni][r]);
                    if (ni * 16 + quad * 4 + r > qloc) p = 0.f;
                    s[ni][r] = p;
                    l += p;
                }
        } else {
            #pragma unroll
            for (int ni = 0; ni < 4; ni++)
                #pragma unroll
                for (int r = 0; r < 4; r++) {
                    float p = exp2f(s[ni][r]);
                    s[ni][r] = p;
                    l += p;
                }
        }
        #pragma unroll
        for (int ni = 0; ni < 4; ni++) {
            uint2 pk;
            pk.x = (unsigned int)f2b(s[ni][0]) | ((unsigned int)f2b(s[ni][1]) << 16);
            pk.y = (unsigned int)f2b(s[ni][2]) | ((unsigned int)f2b(s[ni][3]) << 16);
            *(uint2*)&Pw[lrow * 72 + ni * 16 + quad * 4] = pk;
        }
        bf16x8 p0 = *(const bf16x8*)&Pw[lrow * 72 + quad * 8];
        bf16x8 p1 = *(const bf16x8*)&Pw[lrow * 72 + 32 + quad * 8];
        #pragma unroll
        for (int ni = 0; ni < 4; ni++) {
            bf16x8 vf = *(const bf16x8*)&Vs[buf][0][(ni * 16 + lrow) * 32 + qx8];
            o[ni] = __builtin_amdgcn_mfma_f32_16x16x32_bf16(p0, vf, o[ni], 0, 0, 0);
        }
        #pragma unroll
        for (int ni = 0; ni < 4; ni++) {
            bf16x8 vf = *(const bf16x8*)&Vs[buf][1][(ni * 16 + lrow) * 32 + qx8];
            o[ni] = __builtin_amdgcn_mfma_f32_16x16x32_bf16(p1, vf, o[ni], 0, 0, 0);
        }
    };

    auto epilogue = [&](int qbase) {
        float la = lA, lb = lB;
        la += __shfl_xor(la, 16, 64); la += __shfl_xor(la, 32, 64);
        lb += __shfl_xor(lb, 16, 64); lb += __shfl_xor(lb, 32, 64);
        #pragma unroll
        for (int strip = 0; strip < 2; strip++) {
            f32x4* o = strip ? oB : oA;
            float lv = strip ? lb : la;
            #pragma unroll
            for (int r = 0; r < 4; r++) {
                float lr = __shfl(lv, quad * 4 + r, 64);
                float inv = 1.0f / lr;
                int q = qbase + strip * 64 + wave * 16 + quad * 4 + r;
                #pragma unroll
                for (int ni = 0; ni < 4; ni++)
                    attn_out[((size_t)b * 2048 + q) * 1024 + h * 64 + ni * 16 + lrow] =
                        f2b(o[ni][r] * inv);
            }
        }
    };

    stage(0, 0);

    for (int j = 0; j < ntot; j++) {
        __syncthreads();
        if (j + 1 < ntot) {
            int t = (j + 1 < nktA) ? (j + 1) : (j + 1 - nktA);
            stage(t, (j + 1) & 1);
        }
        int buf = j & 1;
        if (j < nktA) {
            if (j < nktA - 1)
                process(qf[0][0][0], qf[0][0][1], oA, lA, Ps[wave], j == nktA - 2, buf);
            process(qf[0][1][0], qf[0][1][1], oB, lB, Ps[wave + 4], j == nktA - 1, buf);
            if (j == nktA - 1) {
                epilogue(qtA * 128);
                #pragma unroll
                for (int ni = 0; ni < 4; ni++) { oA[ni] = zero; oB[ni] = zero; }
                lA = 0.f; lB = 0.f;
            }
        } else {
            int t = j - nktA;
            if (t < nktB - 1)
                process(qf[1][0][0], qf[1][0][1], oA, lA, Ps[wave], t == nktB - 2, buf);
            process(qf[1][1][0], qf[1][1][1], oB, lB, Ps[wave + 4], t == nktB - 1, buf);
        }
    }
    epilogue(qtB * 128);
}

extern "C" void kernel_launch(void* const* d_in, const int* in_sizes, int n_in,
                              void* d_out, int out_size, void* d_ws, size_t ws_size,
                              hipStream_t stream) {
    const float* x  = (const float*)d_in[0];
    const float* g1 = (const float*)d_in[1];
    const float* g2 = (const float*)d_in[2];
    const float* wq = (const float*)d_in[3];
    const float* wk = (const float*)d_in[4];
    const float* wv = (const float*)d_in[5];
    const float* wo = (const float*)d_in[6];
    const float* w1 = (const float*)d_in[7];
    const float* w2 = (const float*)d_in[8];
    float* out = (float*)d_out;

    const size_t BS = 4096;
    const size_t D = 1024, DFF = 4096;
    const float QSCALE = 0.18033688011112042f;  // 0.125 * log2(e), folded into wq

    char* w = (char*)d_ws;
    unsigned short* xn_b   = (unsigned short*)w; w += BS * D * 2;
    unsigned short* wqkv_b = (unsigned short*)w; w += 3 * D * D * 2;
    unsigned short* qkv_b  = (unsigned short*)w; w += BS * 3 * D * 2;
    unsigned short* vt_b   = (unsigned short*)w; w += BS * D * 2;
    unsigned short* attn_b = (unsigned short*)w; w += BS * D * 2;
    unsigned short* wo_b   = (unsigned short*)w; w += D * D * 2;
    float*          x2     = (float*)w;          w += BS * D * 4;
    unsigned short* xn2_b  = (unsigned short*)w; w += BS * D * 2;
    unsigned short* w1_b   = (unsigned short*)w; w += DFF * D * 2;
    unsigned short* h_b    = (unsigned short*)w; w += BS * DFF * 2;
    unsigned short* w2_b   = (unsigned short*)w; w += D * DFF * 2;

    // all weight casts in one launch (12M elements / 4 per thread; exact grid)
    cast_all_k<<<12288, 256, 0, stream>>>(wq, wk, wv, wo, w1, w2,
                                          wqkv_b, wo_b, w1_b, w2_b, QSCALE);

    rmsnorm_bf16_k<<<(int)BS, 256, 0, stream>>>(x, g1, xn_b);

    // qkv = xn @ [wq;wk;wv]^T   [4096 x 3072]
    gemm_bt<0><<<dim3(24, 32), 256, 0, stream>>>(xn_b, wqkv_b, nullptr, qkv_b, 4096, 3072, 1024);

    // V transpose for attention B-frags
    vtrans_k<<<dim3(32, 32), 256, 0, stream>>>(qkv_b, vt_b);

    // causal flash attention (balanced q-tile pairs, 256 blocks)
    attn_k<<<dim3(8, 32), 256, 0, stream>>>(qkv_b, vt_b, attn_b);

    // x2 = x + attn @ wo^T
    gemm_bt64<<<dim3(16, 32), 256, 0, stream>>>(attn_b, wo_b, x, x2, 4096, 1024, 1024);

    rmsnorm_bf16_k<<<(int)BS, 256, 0, stream>>>(x2, g2, xn2_b);

    // h = gelu(xn2 @ w1^T)   [4096 x 4096]
    gemm_bt<2><<<dim3(32, 32), 256, 0, stream>>>(xn2_b, w1_b, nullptr, h_b, 4096, 4096, 1024);

    // out = x2 + h @ w2^T
    gemm_bt64<<<dim3(16, 32), 256, 0, stream>>>(h_b, w2_b, x2, out, 4096, 1024, 4096);
}